// Round 14
// baseline (7416.106 us; speedup 1.0000x reference)
//
#include <hip/hip_runtime.h>

#define BB 8
#define TT 2000
#define DD 64
#define NN 2000
#define NWG 125
#define COLS 16
#define THREADS 512
#define SROW 2048          // wS LDS row stride (bf16)
#define XST 68

// LDS: wS 16*2048*2=65536, winS 16*68*4=4352, red 8*8*16*4=4096
#define LDS_BYTES (65536 + 4352 + 4096)

typedef __bf16 bf16x8 __attribute__((ext_vector_type(8)));
typedef float f32x4 __attribute__((ext_vector_type(4)));

__device__ __forceinline__ float fast_tanh(float v) {
    float e = __expf(2.0f * v);
    return 1.0f - 2.0f / (e + 1.0f);
}

// ---- uncached (coherence-point) accessors: sc0 sc1 = bypass L1/L2, served by IC ----
__device__ __forceinline__ uint4 ld_uc4(const void* p) {
    uint4 v;
    asm volatile("global_load_dwordx4 %0, %1, off sc0 sc1" : "=v"(v) : "v"(p) : "memory");
    return v;
}
__device__ __forceinline__ void st_uc_u16(void* p, unsigned v) {
    asm volatile("global_store_short %0, %1, off sc0 sc1" :: "v"(p), "v"(v) : "memory");
}
__device__ __forceinline__ void st_uc_u32(void* p, unsigned v) {
    asm volatile("global_store_dword %0, %1, off sc0 sc1" :: "v"(p), "v"(v) : "memory");
}

// 32-lane 2-deep pipelined sweep: each active lane watches 4 consecutive dword
// flags at p..p+12; returns when ALL flags across all active lanes are >= tgt.
// Must be called with a uniform active mask (exec) of the polling lanes.
__device__ __forceinline__ void sweep4_pipelined(const unsigned* p, unsigned tgt) {
    unsigned a0, a1, a2, a3, b0, b1, b2, b3;
    unsigned long long m;
    asm volatile(
        "global_load_dword %0, %9, off sc0 sc1\n\t"
        "global_load_dword %1, %9, off offset:4 sc0 sc1\n\t"
        "global_load_dword %2, %9, off offset:8 sc0 sc1\n\t"
        "global_load_dword %3, %9, off offset:12 sc0 sc1\n\t"
        "global_load_dword %4, %9, off sc0 sc1\n\t"
        "global_load_dword %5, %9, off offset:4 sc0 sc1\n\t"
        "global_load_dword %6, %9, off offset:8 sc0 sc1\n\t"
        "global_load_dword %7, %9, off offset:12 sc0 sc1\n\t"
        "Ls_%=:\n\t"
        "s_waitcnt vmcnt(4)\n\t"
        "v_cmp_le_u32 vcc, %10, %0\n\t"
        "s_mov_b64 %8, vcc\n\t"
        "v_cmp_le_u32 vcc, %10, %1\n\t"
        "s_and_b64 %8, %8, vcc\n\t"
        "v_cmp_le_u32 vcc, %10, %2\n\t"
        "s_and_b64 %8, %8, vcc\n\t"
        "v_cmp_le_u32 vcc, %10, %3\n\t"
        "s_and_b64 %8, %8, vcc\n\t"
        "s_xor_b64 %8, %8, exec\n\t"
        "s_cbranch_scc0 Ld_%=\n\t"
        "global_load_dword %0, %9, off sc0 sc1\n\t"
        "global_load_dword %1, %9, off offset:4 sc0 sc1\n\t"
        "global_load_dword %2, %9, off offset:8 sc0 sc1\n\t"
        "global_load_dword %3, %9, off offset:12 sc0 sc1\n\t"
        "s_waitcnt vmcnt(4)\n\t"
        "v_cmp_le_u32 vcc, %10, %4\n\t"
        "s_mov_b64 %8, vcc\n\t"
        "v_cmp_le_u32 vcc, %10, %5\n\t"
        "s_and_b64 %8, %8, vcc\n\t"
        "v_cmp_le_u32 vcc, %10, %6\n\t"
        "s_and_b64 %8, %8, vcc\n\t"
        "v_cmp_le_u32 vcc, %10, %7\n\t"
        "s_and_b64 %8, %8, vcc\n\t"
        "s_xor_b64 %8, %8, exec\n\t"
        "s_cbranch_scc0 Ld_%=\n\t"
        "global_load_dword %4, %9, off sc0 sc1\n\t"
        "global_load_dword %5, %9, off offset:4 sc0 sc1\n\t"
        "global_load_dword %6, %9, off offset:8 sc0 sc1\n\t"
        "global_load_dword %7, %9, off offset:12 sc0 sc1\n\t"
        "s_branch Ls_%=\n\t"
        "Ld_%=:\n\t"
        "s_waitcnt vmcnt(0)\n\t"
        : "=&v"(a0), "=&v"(a1), "=&v"(a2), "=&v"(a3),
          "=&v"(b0), "=&v"(b1), "=&v"(b2), "=&v"(b3), "=&s"(m)
        : "v"(p), "v"(tgt)
        : "vcc", "memory");
}

// State buffer sG: MFMA-A-fragment order (per gen, 32 KB); granule(kb,b) at
// 16B-index (kb>>2)*32 + (kb&3)*8 + b. Wave w step m reads contiguous 512 B
// region (w*8+m); lane l -> offset ((l>>4)*8 + (l&7))*16. Pad kb>=250 stays 0.
//
// Flags: 8 replicas of the 125 per-wg flags (replica r at frep + r*128 dwords;
// dwords 125..127 of each replica are 0xFFFFFFFF pads). Producer wave lanes
// 0..7 store the wg's flag to all 8 replicas; consumer wg sweeps replica wg&7
// directly (one IC hop, 64 reads/line/iter — no sweeper, no gen).

__global__ void __launch_bounds__(THREADS, 1)
esn_recur(const float* __restrict__ x, const float* __restrict__ Win,
          const float* __restrict__ Wres, char* __restrict__ sgB,
          float* __restrict__ H, unsigned* __restrict__ frep)
{
    extern __shared__ char smraw[];
    __bf16* wS   = (__bf16*)smraw;                 // [16][2048] swizzled: blk^(c&7)
    float*  winS = (float*)(wS + 16 * SROW);       // [16][68]
    float*  red  = winS + 16 * XST;                // [8 waves][8 rows][16 cols]

    const int tid  = threadIdx.x;
    const int wg   = blockIdx.x;
    const int col0 = wg * COLS;
    const int wave = tid >> 6;
    const int lane = tid & 63;

    for (int i = tid; i < LDS_BYTES / 4; i += THREADS) ((unsigned*)smraw)[i] = 0u;
    __syncthreads();

    // one-time: Wres slice transposed, bf16, XOR-swizzled 16B blocks
    {
        const int c = tid & 15, h = c & 7;
        for (int k = tid >> 4; k < NN; k += 32)
            wS[c * SROW + ((((k >> 3) ^ h) << 3) | (k & 7))] =
                (__bf16)Wres[(size_t)k * NN + col0 + c];
    }
    // one-time: Win slice (f32)
    for (int i = tid; i < COLS * DD; i += THREADS) {
        int c = i >> 6, d = i & 63;
        winS[c * XST + d] = Win[(size_t)d * NN + col0 + c];
    }
    __syncthreads();

    const int quad = lane >> 4;
    const int bcol = lane & 15;
    const int hb   = bcol & 7;
    const int fb = lane >> 4, fc = lane & 15;
    const int cg = col0 + fc;
    const int pReg = cg >> 5, pSub = (cg >> 3) & 3, pJ = (cg & 7) * 2;
    const size_t pOff0 = (((size_t)(pReg * 32 + pSub * 8 + fb    )) << 4) + pJ;
    const size_t pOff1 = (((size_t)(pReg * 32 + pSub * 8 + fb + 4)) << 4) + pJ;
    const size_t aLane = (size_t)((quad * 8 + (lane & 7)) << 4);
    // consumer sweep: lanes 0..31 of wave 0 watch replica (wg&7), 4 flags each
    const unsigned* swp = frep + (wg & 7) * 128 + lane * 4;
    // producer flag replication: lane r (<8) stores to replica r, slot wg
    unsigned* fdst = frep + lane * 128 + wg;

    // ---- hoist B fragments into registers for the whole kernel ----
    unsigned bw[8][4];
    {
        const __bf16* bBase = wS + bcol * SROW;
        const int blk0 = wave * 32 + quad;
        #pragma unroll
        for (int m = 0; m < 8; ++m) {
            uint4 v = *(const uint4*)(bBase + (((blk0 + m * 4) ^ hb) << 3));
            bw[m][0] = v.x; bw[m][1] = v.y; bw[m][2] = v.z; bw[m][3] = v.w;
            asm volatile("" : "+v"(bw[m][0]), "+v"(bw[m][1]),
                              "+v"(bw[m][2]), "+v"(bw[m][3]));
        }
    }

    for (int t = 0; t < TT; ++t) {
        // x@Win partials (producer wave only) — L2-cached x, off the signal path
        float xa0 = 0.f, xa1 = 0.f;
        if (wave == 1) {
            const float4* xr0 = (const float4*)(x + ((size_t)fb * TT + t) * DD);
            const float4* xr1 = (const float4*)(x + ((size_t)(fb + 4) * TT + t) * DD);
            const float4* wv  = (const float4*)(winS + fc * XST);
            #pragma unroll
            for (int d4 = 0; d4 < 16; ++d4) {
                float4 w = wv[d4];
                float4 u0 = xr0[d4], u1 = xr1[d4];
                xa0 = fmaf(u0.x, w.x, xa0); xa0 = fmaf(u0.y, w.y, xa0);
                xa0 = fmaf(u0.z, w.z, xa0); xa0 = fmaf(u0.w, w.w, xa0);
                xa1 = fmaf(u1.x, w.x, xa1); xa1 = fmaf(u1.y, w.y, xa1);
                xa1 = fmaf(u1.z, w.z, xa1); xa1 = fmaf(u1.w, w.w, xa1);
            }
        }

        f32x4 acc = {0.f, 0.f, 0.f, 0.f};
        if (t > 0) {
            // ONE-hop signal: wave 0 lanes 0..31 sweep replica (wg&7) directly
            if (wave == 0 && lane < 32) {
                sweep4_pipelined(swp, (unsigned)t);
            }
            __builtin_amdgcn_s_barrier();          // release: state_t certified at IC

            // A-operand: 8 contiguous coalesced 512 B region loads -> MFMA frags
            const char* aB = sgB + (size_t)(t & 1) * 32768 + wave * 4096 + aLane;
            uint4 a0 = ld_uc4(aB);
            uint4 a1 = ld_uc4(aB + 512);
            uint4 a2 = ld_uc4(aB + 1024);
            uint4 a3 = ld_uc4(aB + 1536);
            uint4 a4 = ld_uc4(aB + 2048);
            uint4 a5 = ld_uc4(aB + 2560);
            uint4 a6 = ld_uc4(aB + 3072);
            uint4 a7 = ld_uc4(aB + 3584);
            asm volatile("s_waitcnt vmcnt(0)" ::: "memory");
            __builtin_amdgcn_sched_barrier(0);     // rule #18: pin MFMA below wait

            #define MSTEP(mm, areg) { \
                uint4 bu = make_uint4(bw[mm][0], bw[mm][1], bw[mm][2], bw[mm][3]); \
                acc = __builtin_amdgcn_mfma_f32_16x16x32_bf16( \
                    __builtin_bit_cast(bf16x8, areg), \
                    __builtin_bit_cast(bf16x8, bu), acc, 0, 0, 0); }
            MSTEP(0, a0) MSTEP(1, a1) MSTEP(2, a2) MSTEP(3, a3)
            MSTEP(4, a4) MSTEP(5, a5) MSTEP(6, a6) MSTEP(7, a7)
            #undef MSTEP
        }
        if (lane < 32) {
            const int r0 = (lane >> 4) * 4;
            #pragma unroll
            for (int i = 0; i < 4; ++i)
                red[(wave * 8 + r0 + i) * 16 + bcol] = acc[i];
        }
        __syncthreads();

        // finish (wave 1 only): 2 outputs/thread; drain own stores, then
        // replicate the flag to 8 lines (lanes 0..7, fire-and-forget).
        if (wave == 1) {
            float a0s = xa0, a1s = xa1;
            #pragma unroll
            for (int w = 0; w < 8; ++w) {
                a0s += red[(w * 8 + fb    ) * 16 + fc];
                a1s += red[(w * 8 + fb + 4) * 16 + fc];
            }
            float s0 = fast_tanh(a0s);
            float s1 = fast_tanh(a1s);
            if (t < TT - 1) {
                __bf16 b0 = (__bf16)s0, b1 = (__bf16)s1;
                unsigned short u0, u1;
                __builtin_memcpy(&u0, &b0, 2);
                __builtin_memcpy(&u1, &b1, 2);
                char* dstG = sgB + (size_t)((t + 1) & 1) * 32768;
                st_uc_u16(dstG + pOff0, (unsigned)u0);
                st_uc_u16(dstG + pOff1, (unsigned)u1);
                asm volatile("s_waitcnt vmcnt(0)" ::: "memory");  // state at IC
                if (lane < 8) st_uc_u32(fdst, (unsigned)(t + 1));
            }
            float h0 = (fc & 1) ? s0 : s0 * s0;   // even global col -> square
            float h1 = (fc & 1) ? s1 : s1 * s1;
            H[((size_t)t * BB + fb    ) * NN + col0 + fc] = h0;   // off signal path
            H[((size_t)t * BB + fb + 4) * NN + col0 + fc] = h1;
        }
    }
}

// out[b,t,:] = H[t,b,:] @ Wout  (augmentation already applied in H)
__global__ void __launch_bounds__(256, 1)
esn_out(const float* __restrict__ H, const float* __restrict__ Wout,
        float* __restrict__ out)
{
    __shared__ float Hs[64 * 84];
    __shared__ float Ws[80 * 64];
    const int tid = threadIdx.x;
    const int r0  = blockIdx.x * 64;      // global row = t*8 + b
    const int tr  = tid >> 4;             // 0..15
    const int tc  = tid & 15;             // 0..15
    float acc[4][4] = {{0.f}};

    for (int k0 = 0; k0 < NN; k0 += 80) {
        __syncthreads();
        #pragma unroll
        for (int j = 0; j < 5; ++j) {
            int idx = j * 256 + tid;               // 0..1279
            int r = idx / 20, q = idx % 20;
            *(float4*)&Hs[r * 84 + q * 4] =
                *(const float4*)&H[(size_t)(r0 + r) * NN + k0 + q * 4];
        }
        #pragma unroll
        for (int j = 0; j < 5; ++j) {
            int idx = j * 256 + tid;
            int kk = idx >> 4, c4 = idx & 15;
            *(float4*)&Ws[kk * 64 + c4 * 4] =
                *(const float4*)&Wout[(size_t)(k0 + kk) * DD + c4 * 4];
        }
        __syncthreads();
        for (int kk = 0; kk < 80; ++kk) {
            float4 wv = *(const float4*)&Ws[kk * 64 + tc * 4];
            #pragma unroll
            for (int i = 0; i < 4; ++i) {
                float hv = Hs[(tr + 16 * i) * 84 + kk];
                acc[i][0] = fmaf(hv, wv.x, acc[i][0]);
                acc[i][1] = fmaf(hv, wv.y, acc[i][1]);
                acc[i][2] = fmaf(hv, wv.z, acc[i][2]);
                acc[i][3] = fmaf(hv, wv.w, acc[i][3]);
            }
        }
    }
    #pragma unroll
    for (int i = 0; i < 4; ++i) {
        int rg = r0 + tr + 16 * i;
        int t = rg >> 3, b = rg & 7;
        *(float4*)&out[((size_t)b * TT + t) * DD + tc * 4] =
            make_float4(acc[i][0], acc[i][1], acc[i][2], acc[i][3]);
    }
}

extern "C" void kernel_launch(void* const* d_in, const int* in_sizes, int n_in,
                              void* d_out, int out_size, void* d_ws, size_t ws_size,
                              hipStream_t stream)
{
    const float* x    = (const float*)d_in[0];
    const float* Win  = (const float*)d_in[1];
    const float* Wres = (const float*)d_in[2];
    const float* Wout = (const float*)d_in[3];
    float* out = (float*)d_out;

    char* ws = (char*)d_ws;
    unsigned* frep = (unsigned*)ws;                  // 8 replicas * 128 dwords = 4 KB
    char* sG  = ws + 4096;                           // 2 gens * 32 KB fragment-order state
    float* H  = (float*)(ws + 4096 + 65536);         // 2000*8*2000 f32 = 128 MB

    // zero flags + state (incl. K-pad granules), then set replica pads to ~0
    (void)hipMemsetAsync(d_ws, 0, 4096 + 65536, stream);
    for (int r = 0; r < 8; ++r)
        (void)hipMemsetAsync(ws + r * 512 + 500, 0xFF, 12, stream);

    (void)hipFuncSetAttribute((const void*)esn_recur,
                              hipFuncAttributeMaxDynamicSharedMemorySize, LDS_BYTES);
    esn_recur<<<NWG, THREADS, LDS_BYTES, stream>>>(x, Win, Wres, sG, H, frep);
    esn_out<<<250, 256, 0, stream>>>(H, Wout, out);
}